// Round 1
// baseline (198.046 us; speedup 1.0000x reference)
//
#include <hip/hip_runtime.h>
#include <math.h>

#define NBLK 256
#define N_MAX 2048

// Accumulate one atom (x0,x1,x2)/(y0,y1,y2) with validity mask m (0.0 or 1.0)
#define ACC_ATOM(X0,X1,X2,Y0,Y1,Y2,M) do {                          \
    const float m_ = (M);                                           \
    const float x0 = (X0)*m_, x1 = (X1)*m_, x2 = (X2)*m_;           \
    const float y0 = (Y0)*m_, y1 = (Y1)*m_, y2 = (Y2)*m_;           \
    acc[0]  += x0;    acc[1]  += x1;    acc[2]  += x2;              \
    acc[3]  += y0;    acc[4]  += y1;    acc[5]  += y2;              \
    acc[6]  += x0*y0; acc[7]  += x0*y1; acc[8]  += x0*y2;           \
    acc[9]  += x1*y0; acc[10] += x1*y1; acc[11] += x1*y2;           \
    acc[12] += x2*y0; acc[13] += x2*y1; acc[14] += x2*y2;           \
    acc[15] += x0*x0 + x1*x1 + x2*x2;                               \
    acc[16] += y0*y0 + y1*y1 + y2*y2;                               \
} while (0)

__global__ __launch_bounds__(NBLK) void kabsch_rmsd_kernel(
    const float* __restrict__ X, const float* __restrict__ Y,
    const int* __restrict__ num_atoms, float* __restrict__ out)
{
    const int b = blockIdx.x;
    const int t = threadIdx.x;
    const int n = num_atoms[b];

    const float4* __restrict__ x4 =
        reinterpret_cast<const float4*>(X + (size_t)b * (3 * N_MAX));
    const float4* __restrict__ y4 =
        reinterpret_cast<const float4*>(Y + (size_t)b * (3 * N_MAX));

    // 0..2: Sx  3..5: Sy  6..14: Sxy row-major  15: Sxx  16: Syy
    float acc[17];
#pragma unroll
    for (int i = 0; i < 17; ++i) acc[i] = 0.0f;

    // 4 atoms per thread per iteration = 3 float4 loads per input row.
    for (int a0 = 4 * t; a0 < n; a0 += 4 * NBLK) {
        const int fi = 3 * (a0 >> 2);
        const float4 xa = x4[fi + 0], xb = x4[fi + 1], xc = x4[fi + 2];
        const float4 ya = y4[fi + 0], yb = y4[fi + 1], yc = y4[fi + 2];
        const float m1 = (a0 + 1 < n) ? 1.0f : 0.0f;
        const float m2 = (a0 + 2 < n) ? 1.0f : 0.0f;
        const float m3 = (a0 + 3 < n) ? 1.0f : 0.0f;
        ACC_ATOM(xa.x, xa.y, xa.z, ya.x, ya.y, ya.z, 1.0f);   // a0 < n guaranteed
        ACC_ATOM(xa.w, xb.x, xb.y, ya.w, yb.x, yb.y, m1);
        ACC_ATOM(xb.z, xb.w, xc.x, yb.z, yb.w, yc.x, m2);
        ACC_ATOM(xc.y, xc.z, xc.w, yc.y, yc.z, yc.w, m3);
    }

    // wave(64)-level shuffle reduction
#pragma unroll
    for (int i = 0; i < 17; ++i) {
#pragma unroll
        for (int off = 32; off > 0; off >>= 1)
            acc[i] += __shfl_down(acc[i], off);
    }

    __shared__ float lds[17 * 4];  // 4 waves per block
    const int wave = t >> 6;
    const int lane = t & 63;
    if (lane == 0) {
#pragma unroll
        for (int i = 0; i < 17; ++i) lds[i * 4 + wave] = acc[i];
    }
    __syncthreads();

    if (t == 0) {
        double s[17];
#pragma unroll
        for (int i = 0; i < 17; ++i)
            s[i] = (double)lds[i * 4 + 0] + (double)lds[i * 4 + 1] +
                   (double)lds[i * 4 + 2] + (double)lds[i * 4 + 3];

        const double dn = (double)n;
        const double Sx0 = s[0], Sx1 = s[1], Sx2 = s[2];
        const double Sy0 = s[3], Sy1 = s[4], Sy2 = s[5];

        // centered cross-covariance C_ij = Sxy_ij - Sx_i*Sy_j/n
        double C[3][3];
        C[0][0] = s[6]  - Sx0 * Sy0 / dn;
        C[0][1] = s[7]  - Sx0 * Sy1 / dn;
        C[0][2] = s[8]  - Sx0 * Sy2 / dn;
        C[1][0] = s[9]  - Sx1 * Sy0 / dn;
        C[1][1] = s[10] - Sx1 * Sy1 / dn;
        C[1][2] = s[11] - Sx1 * Sy2 / dn;
        C[2][0] = s[12] - Sx2 * Sy0 / dn;
        C[2][1] = s[13] - Sx2 * Sy1 / dn;
        C[2][2] = s[14] - Sx2 * Sy2 / dn;

        const double gx = s[15] - (Sx0*Sx0 + Sx1*Sx1 + Sx2*Sx2) / dn;
        const double gy = s[16] - (Sy0*Sy0 + Sy1*Sy1 + Sy2*Sy2) / dn;

        const double det =
            C[0][0] * (C[1][1]*C[2][2] - C[1][2]*C[2][1]) -
            C[0][1] * (C[1][0]*C[2][2] - C[1][2]*C[2][0]) +
            C[0][2] * (C[1][0]*C[2][1] - C[1][1]*C[2][0]);

        // A = C^T C (symmetric PSD); singular values of C = sqrt(eig(A))
        double A00 = C[0][0]*C[0][0] + C[1][0]*C[1][0] + C[2][0]*C[2][0];
        double A11 = C[0][1]*C[0][1] + C[1][1]*C[1][1] + C[2][1]*C[2][1];
        double A22 = C[0][2]*C[0][2] + C[1][2]*C[1][2] + C[2][2]*C[2][2];
        double A01 = C[0][0]*C[0][1] + C[1][0]*C[1][1] + C[2][0]*C[2][1];
        double A02 = C[0][0]*C[0][2] + C[1][0]*C[1][2] + C[2][0]*C[2][2];
        double A12 = C[0][1]*C[0][2] + C[1][1]*C[1][2] + C[2][1]*C[2][2];

        // closed-form symmetric 3x3 eigenvalues (trigonometric method)
        double e0, e1, e2;
        const double q  = (A00 + A11 + A22) / 3.0;
        const double p1 = A01*A01 + A02*A02 + A12*A12;
        const double p2 = (A00-q)*(A00-q) + (A11-q)*(A11-q) + (A22-q)*(A22-q)
                          + 2.0 * p1;
        if (p2 <= 0.0) {
            e0 = e1 = e2 = q;
        } else {
            const double p = sqrt(p2 / 6.0);
            const double ip = 1.0 / p;
            const double b00 = (A00 - q) * ip, b11 = (A11 - q) * ip,
                         b22 = (A22 - q) * ip;
            const double b01 = A01 * ip, b02 = A02 * ip, b12 = A12 * ip;
            double r = 0.5 * (b00 * (b11*b22 - b12*b12)
                            - b01 * (b01*b22 - b12*b02)
                            + b02 * (b01*b12 - b11*b02));
            r = fmin(1.0, fmax(-1.0, r));
            const double phi = acos(r) / 3.0;
            e0 = q + 2.0 * p * cos(phi);                        // largest
            e2 = q + 2.0 * p * cos(phi + 2.0943951023931953);   // smallest
            e1 = 3.0 * q - e0 - e2;
        }

        const double s0 = sqrt(fmax(e0, 0.0));
        const double s1 = sqrt(fmax(e1, 0.0));
        const double s2 = sqrt(fmax(e2, 0.0));
        const double dsign = (det < 0.0) ? -1.0 : 1.0;
        const double trace = s0 + s1 + dsign * s2;

        const double msd = (gx + gy - 2.0 * trace) / dn;
        out[b] = (float)sqrt(fmax(msd, 0.0));
    }
}

extern "C" void kernel_launch(void* const* d_in, const int* in_sizes, int n_in,
                              void* d_out, int out_size, void* d_ws, size_t ws_size,
                              hipStream_t stream) {
    const float* coords_input  = (const float*)d_in[0];
    const float* coords_target = (const float*)d_in[1];
    const int*   num_atoms     = (const int*)d_in[2];
    float* out = (float*)d_out;

    const int B = out_size;  // 4096
    kabsch_rmsd_kernel<<<B, NBLK, 0, stream>>>(coords_input, coords_target,
                                               num_atoms, out);
}